// Round 3
// baseline (21.743 us; speedup 1.0000x reference)
//
#include <hip/hip_runtime.h>

// Locally-connected 3D conv (unshared weights), fp32.
// x: (2,24,24,24,8)  kernel: (10648,216,8) = 73.6 MB (the stream)  bias: (22,22,22,8)
// out: (2,22,22,22,8)
//
// 4 output locations (p) per wave, 16 per block, 666 blocks. Two-stage register
// pipeline: while FMA/reduce of p_i runs, p_{i+1}'s 7 weight float4s + 2 x float4s
// are in flight. x issued BEFORE W each stage so the staging ds_write's vmcnt wait
// (in-order retirement) does not drain the weight-load queue.

constexpr int P_TOT = 22 * 22 * 22;      // 10648
constexpr int KTOT  = 216;               // 3*3*3*8
constexpr int XB    = 24 * 24 * 24 * 8;  // batch stride of x
constexpr int NV4   = 432;               // float4 per p (216*8/4)
constexpr int PPW   = 4;                 // p per wave
constexpr int PPB   = 16;                // p per block
constexpr int NBLK  = (P_TOT + PPB - 1) / PPB;  // 666 (last block partial)

__global__ __launch_bounds__(256) void lc3d_kernel(
    const float* __restrict__ x,
    const float* __restrict__ kern,
    const float* __restrict__ bias,
    float* __restrict__ out)
{
    __shared__ float xl[4][2][2 * KTOT];   // [wave][buf][b*216+k] = 13.8 KB

    const int tid  = threadIdx.x;
    const int wave = tid >> 6;
    const int lane = tid & 63;
    const int p0   = blockIdx.x * PPB + wave * PPW;

    float* xw0 = xl[wave][0];
    float* xw1 = xl[wave][1];

    // Per-lane staging geometry (constant across p): 108 float4s in 2 rounds.
    // t4 -> seg=t4/6 (0..17), wi=t4%6; seg -> b=seg/9, s=seg%9=di*3+dj.
    const int t4b  = lane + 64;
    const bool mB  = (t4b < 108);
    const int segA = lane / 6,      wiA = lane - segA * 6;
    const int bA   = segA / 9,      sA  = segA - bA * 9;
    const int diA  = sA / 3,        djA = sA - diA * 3;
    const int xoffA = bA * XB + diA * 4608 + djA * 192 + wiA * 4;
    const int loffA = segA * 24 + wiA * 4;
    const int segB = t4b / 6,       wiB = t4b - segB * 6;
    const int bB   = segB / 9,      sB  = segB - bB * 9;
    const int diB  = sB / 3,        djB = sB - diB * 3;
    const int xoffB = bB * XB + diB * 4608 + djB * 192 + wiB * 4;
    const int loffB = segB * 24 + wiB * 4;

    const int k0 = lane >> 1;   // float4 j covers k=j>>1 (F=8: two float4 per k)

    float4 bw[2][7];            // double-buffered weight chunks
    float4 bxA[2], bxB[2];      // double-buffered x staging regs

    auto xbase_of = [](int p) {
        const int oz = p % 22, t = p / 22, oc = t % 22, orr = t / 22;
        return orr * 4608 + oc * 192 + oz * 8;   // x strides: d=4608,h=192,w=8,c=1
    };
    auto loadX = [&](int p, float4& a, float4& b) {
        const int xb = xbase_of(p);
        a = *reinterpret_cast<const float4*>(x + xb + xoffA);
        if (mB) b = *reinterpret_cast<const float4*>(x + xb + xoffB);
    };
    auto loadW = [&](int p, float4* dst) {
        const float4* kp = reinterpret_cast<const float4*>(kern) + (size_t)p * NV4;
        #pragma unroll
        for (int i = 0; i < 6; ++i) dst[i] = kp[lane + 64 * i];
        if (lane < 48) dst[6] = kp[lane + 384];
    };
    auto writeX = [&](float* xw, const float4& a, const float4& b) {
        *reinterpret_cast<float4*>(xw + loffA) = a;
        if (mB) *reinterpret_cast<float4*>(xw + loffB) = b;
    };

    // ---- prologue: stage p0 ----
    if (p0 < P_TOT) {
        loadX(p0, bxA[0], bxB[0]);     // x first: oldest in vmcnt queue
        loadW(p0, bw[0]);
        writeX(xw0, bxA[0], bxB[0]);   // waits only the 2 x loads (in-order vmcnt)
    }

    #pragma unroll
    for (int i = 0; i < PPW; ++i) {
        const int p = p0 + i;
        if (p >= P_TOT) break;                    // wave-uniform
        const int cur = i & 1;
        float* xwc = (cur == 0) ? xw0 : xw1;
        float* xwn = (cur == 0) ? xw1 : xw0;
        const bool pf = (i + 1 < PPW) && (p + 1 < P_TOT);

        if (pf) {                                  // issue next stage: x first, then W
            loadX(p + 1, bxA[cur ^ 1], bxB[cur ^ 1]);
            loadW(p + 1, bw[cur ^ 1]);
        }

        // ---- compute p from bw[cur] and xwc ----
        float4 a0 = make_float4(0.f, 0.f, 0.f, 0.f);
        float4 a1 = make_float4(0.f, 0.f, 0.f, 0.f);
        auto fma8 = [&](const float4& kv, int k) {
            const float x0 = xwc[k];
            const float x1 = xwc[KTOT + k];
            a0.x = fmaf(x0, kv.x, a0.x);  a0.y = fmaf(x0, kv.y, a0.y);
            a0.z = fmaf(x0, kv.z, a0.z);  a0.w = fmaf(x0, kv.w, a0.w);
            a1.x = fmaf(x1, kv.x, a1.x);  a1.y = fmaf(x1, kv.y, a1.y);
            a1.z = fmaf(x1, kv.z, a1.z);  a1.w = fmaf(x1, kv.w, a1.w);
        };
        #pragma unroll
        for (int c = 0; c < 6; ++c) fma8(bw[cur][c], k0 + 32 * c);
        if (lane < 48) fma8(bw[cur][6], k0 + 192);

        if (pf) writeX(xwn, bxA[cur ^ 1], bxB[cur ^ 1]);  // waits x(p+1) only; W(p+1) stays in flight

        // ---- reduce across same-parity lanes (overlaps W(p+1) latency) ----
        #pragma unroll
        for (int m = 2; m <= 32; m <<= 1) {
            a0.x += __shfl_xor(a0.x, m, 64);  a0.y += __shfl_xor(a0.y, m, 64);
            a0.z += __shfl_xor(a0.z, m, 64);  a0.w += __shfl_xor(a0.w, m, 64);
            a1.x += __shfl_xor(a1.x, m, 64);  a1.y += __shfl_xor(a1.y, m, 64);
            a1.z += __shfl_xor(a1.z, m, 64);  a1.w += __shfl_xor(a1.w, m, 64);
        }

        if (lane < 2) {
            const int fb = lane * 4;          // lane0 -> f0..3, lane1 -> f4..7
            const float4 bv = *reinterpret_cast<const float4*>(bias + (size_t)p * 8 + fb);
            float4 o0, o1;
            o0.x = a0.x + bv.x;  o0.y = a0.y + bv.y;  o0.z = a0.z + bv.z;  o0.w = a0.w + bv.w;
            o1.x = a1.x + bv.x;  o1.y = a1.y + bv.y;  o1.z = a1.z + bv.z;  o1.w = a1.w + bv.w;
            *reinterpret_cast<float4*>(out + (size_t)p * 8 + fb) = o0;
            *reinterpret_cast<float4*>(out + (size_t)P_TOT * 8 + (size_t)p * 8 + fb) = o1;
        }
    }
}

extern "C" void kernel_launch(void* const* d_in, const int* in_sizes, int n_in,
                              void* d_out, int out_size, void* d_ws, size_t ws_size,
                              hipStream_t stream) {
    const float* x    = (const float*)d_in[0];
    const float* kern = (const float*)d_in[1];
    const float* bias = (const float*)d_in[2];
    float* out        = (float*)d_out;

    lc3d_kernel<<<NBLK, 256, 0, stream>>>(x, kern, bias, out);
}

// Round 4
// 18.673 us; speedup vs baseline: 1.1644x; 1.1644x over previous
//
#include <hip/hip_runtime.h>

// Locally-connected 3D conv (unshared weights), fp32.
// x: (2,24,24,24,8)  kernel: (10648,216,8) = 73.6 MB (the stream)  bias: (22,22,22,8)
// out: (2,22,22,22,8)
//
// One wave per output location p (R2 structure). Wave stages its 2x216 x-patch
// into LDS (k-linear) with coalesced float4 loads, streams kernel[p] as 432
// contiguous float4s. NEW in R4: the 40-op shuffle butterfly is replaced by an
// LDS transpose reduce (2 ds_write_b128 + 8 ds_read_b32 + 2 shfl), shrinking
// the per-wave DS-pipe load from ~56 to ~28 ops and shortening the wave tail.

constexpr int P_TOT = 22 * 22 * 22;      // 10648
constexpr int KTOT  = 216;               // 3*3*3*8
constexpr int XB    = 24 * 24 * 24 * 8;  // batch stride of x
constexpr int NV4   = 432;               // float4 per p

__global__ __launch_bounds__(256) void lc3d_kernel(
    const float* __restrict__ x,
    const float* __restrict__ kern,
    const float* __restrict__ bias,
    float* __restrict__ out)
{
    __shared__ float xl[4][2 * KTOT];    // per-wave patch, k-linear: [b*216+k]
    __shared__ float pr[4][1024];        // per-wave partials: [((b*2+c)*32+s)*4+fi]

    const int tid  = threadIdx.x;
    const int wave = tid >> 6;
    const int lane = tid & 63;
    const int p    = blockIdx.x * 4 + wave;   // grid exact: 10648 = 2662*4

    const int oz  = p % 22;
    const int t   = p / 22;
    const int oc  = t % 22;
    const int orr = t / 22;
    const int xbase = orr * 4608 + oc * 192 + oz * 8;  // x strides: d=4608,h=192,w=8,c=1

    float* xw = xl[wave];

    // ---- stage both patches (b=0,1) into LDS, k-linear ----
    // 108 float4s: t4 -> seg=t4/6 (0..17), wi=t4%6; seg -> b=seg/9, s=di*3+dj.
    #pragma unroll
    for (int r = 0; r < 2; ++r) {
        const int t4 = lane + r * 64;
        if (t4 < 108) {
            const int seg = t4 / 6;
            const int wi  = t4 - seg * 6;
            const int b   = seg / 9;
            const int s   = seg - b * 9;
            const int di  = s / 3;
            const int dj  = s - di * 3;
            const float4 v = *reinterpret_cast<const float4*>(
                x + (size_t)b * XB + xbase + di * 4608 + dj * 192 + wi * 4);
            *reinterpret_cast<float4*>(xw + seg * 24 + wi * 4) = v;
        }
    }
    // No __syncthreads: each wave touches only its own LDS slices.

    const float4* kp4 = reinterpret_cast<const float4*>(kern) + (size_t)p * NV4;
    const int k0 = lane >> 1;             // float4 j covers k=j>>1, f-half = j&1

    float4 a0 = make_float4(0.f, 0.f, 0.f, 0.f);   // b=0, fields (lane&1)*4 ..+3
    float4 a1 = make_float4(0.f, 0.f, 0.f, 0.f);   // b=1

    auto body = [&](int j, int k) {
        const float4 kv = kp4[j];
        const float x0 = xw[k];
        const float x1 = xw[KTOT + k];
        a0.x = fmaf(x0, kv.x, a0.x);  a0.y = fmaf(x0, kv.y, a0.y);
        a0.z = fmaf(x0, kv.z, a0.z);  a0.w = fmaf(x0, kv.w, a0.w);
        a1.x = fmaf(x1, kv.x, a1.x);  a1.y = fmaf(x1, kv.y, a1.y);
        a1.z = fmaf(x1, kv.z, a1.z);  a1.w = fmaf(x1, kv.w, a1.w);
    };

    #pragma unroll
    for (int i = 0; i < 6; ++i) body(lane + 64 * i, k0 + 32 * i);  // 384 float4s
    if (lane < 48) body(lane + 384, k0 + 192);                     // tail -> 432

    // ---- LDS transpose reduce ----
    // Store: lane (c=lane&1, s=lane>>1) holds partials for f = c*4+fi over
    // k-strip s. Layout pr[((b*2+c)*32+s)*4+fi] -> two contiguous b128 writes.
    {
        const int c = lane & 1, s = lane >> 1;
        float* pw = pr[wave];
        *reinterpret_cast<float4*>(pw + ((0 + c) * 32 + s) * 4) = a0;
        *reinterpret_cast<float4*>(pw + ((2 + c) * 32 + s) * 4) = a1;

        // Read: lane -> output o = lane&15 (b=o>>3, f=o&7), q = lane>>4;
        // sums s in {q+4t}. Banks (4q+16t+fi): 16 distinct/step, 4-way max.
        const int o  = lane & 15;
        const int b  = o >> 3;
        const int f  = o & 7;
        const int cc = f >> 2;
        const int fi = f & 3;
        const int q  = lane >> 4;
        const float* prb = pw + (b * 2 + cc) * 128 + fi;
        float v = 0.f;
        #pragma unroll
        for (int tt = 0; tt < 8; ++tt)
            v += prb[(q + 4 * tt) * 4];
        v += __shfl_xor(v, 16, 64);
        v += __shfl_xor(v, 32, 64);

        if (lane < 16)
            out[(size_t)b * (P_TOT * 8) + (size_t)p * 8 + f] = v + bias[p * 8 + f];
    }
}

extern "C" void kernel_launch(void* const* d_in, const int* in_sizes, int n_in,
                              void* d_out, int out_size, void* d_ws, size_t ws_size,
                              hipStream_t stream) {
    const float* x    = (const float*)d_in[0];
    const float* kern = (const float*)d_in[1];
    const float* bias = (const float*)d_in[2];
    float* out        = (float*)d_out;

    lc3d_kernel<<<P_TOT / 4, 256, 0, stream>>>(x, kern, bias, out);
}

// Round 5
// 18.298 us; speedup vs baseline: 1.1883x; 1.0205x over previous
//
#include <hip/hip_runtime.h>

// Locally-connected 3D conv (unshared weights), fp32.
// x: (2,24,24,24,8)  kernel: (10648,216,8) = 73.6 MB (the stream)  bias: (22,22,22,8)
// out: (2,22,22,22,8)
//
// R4 structure (one wave per p, LDS x-staging, LDS transpose reduce) plus a
// bijective XCD-aware blockIdx swizzle (T1, m204 form): each XCD gets one
// contiguous ~9.2 MB slice of the weight stream instead of a 27.6 KB-granular
// strided walk over all 73.6 MB.

constexpr int P_TOT = 22 * 22 * 22;      // 10648
constexpr int KTOT  = 216;               // 3*3*3*8
constexpr int XB    = 24 * 24 * 24 * 8;  // batch stride of x
constexpr int NV4   = 432;               // float4 per p
constexpr int NBLK  = P_TOT / 4;         // 2662
constexpr int NXCD  = 8;
constexpr int QX    = NBLK / NXCD;       // 332
constexpr int RX    = NBLK % NXCD;       // 6

__global__ __launch_bounds__(256) void lc3d_kernel(
    const float* __restrict__ x,
    const float* __restrict__ kern,
    const float* __restrict__ bias,
    float* __restrict__ out)
{
    __shared__ float xl[4][2 * KTOT];    // per-wave patch, k-linear: [b*216+k]
    __shared__ float pr[4][1024];        // per-wave partials

    // Bijective XCD-chunked swizzle: xcd = bid%8 owns a contiguous range.
    const int bid  = blockIdx.x;
    const int xcd  = bid & 7;
    const int idx  = bid >> 3;
    const int wgid = (xcd < RX) ? xcd * (QX + 1) + idx
                                : RX * (QX + 1) + (xcd - RX) * QX + idx;

    const int tid  = threadIdx.x;
    const int wave = tid >> 6;
    const int lane = tid & 63;
    const int p    = wgid * 4 + wave;

    const int oz  = p % 22;
    const int t   = p / 22;
    const int oc  = t % 22;
    const int orr = t / 22;
    const int xbase = orr * 4608 + oc * 192 + oz * 8;  // x strides: d=4608,h=192,w=8,c=1

    float* xw = xl[wave];

    // ---- stage both patches (b=0,1) into LDS, k-linear ----
    #pragma unroll
    for (int r = 0; r < 2; ++r) {
        const int t4 = lane + r * 64;
        if (t4 < 108) {
            const int seg = t4 / 6;
            const int wi  = t4 - seg * 6;
            const int b   = seg / 9;
            const int s   = seg - b * 9;
            const int di  = s / 3;
            const int dj  = s - di * 3;
            const float4 v = *reinterpret_cast<const float4*>(
                x + (size_t)b * XB + xbase + di * 4608 + dj * 192 + wi * 4);
            *reinterpret_cast<float4*>(xw + seg * 24 + wi * 4) = v;
        }
    }
    // No __syncthreads: each wave touches only its own LDS slices.

    const float4* kp4 = reinterpret_cast<const float4*>(kern) + (size_t)p * NV4;
    const int k0 = lane >> 1;             // float4 j covers k=j>>1, f-half = j&1

    float4 a0 = make_float4(0.f, 0.f, 0.f, 0.f);   // b=0, fields (lane&1)*4 ..+3
    float4 a1 = make_float4(0.f, 0.f, 0.f, 0.f);   // b=1

    auto body = [&](int j, int k) {
        const float4 kv = kp4[j];
        const float x0 = xw[k];
        const float x1 = xw[KTOT + k];
        a0.x = fmaf(x0, kv.x, a0.x);  a0.y = fmaf(x0, kv.y, a0.y);
        a0.z = fmaf(x0, kv.z, a0.z);  a0.w = fmaf(x0, kv.w, a0.w);
        a1.x = fmaf(x1, kv.x, a1.x);  a1.y = fmaf(x1, kv.y, a1.y);
        a1.z = fmaf(x1, kv.z, a1.z);  a1.w = fmaf(x1, kv.w, a1.w);
    };

    #pragma unroll
    for (int i = 0; i < 6; ++i) body(lane + 64 * i, k0 + 32 * i);  // 384 float4s
    if (lane < 48) body(lane + 384, k0 + 192);                     // tail -> 432

    // ---- LDS transpose reduce ----
    {
        const int c = lane & 1, s = lane >> 1;
        float* pw = pr[wave];
        *reinterpret_cast<float4*>(pw + ((0 + c) * 32 + s) * 4) = a0;
        *reinterpret_cast<float4*>(pw + ((2 + c) * 32 + s) * 4) = a1;

        const int o  = lane & 15;
        const int b  = o >> 3;
        const int f  = o & 7;
        const int cc = f >> 2;
        const int fi = f & 3;
        const int q  = lane >> 4;
        const float* prb = pw + (b * 2 + cc) * 128 + fi;
        float v = 0.f;
        #pragma unroll
        for (int tt = 0; tt < 8; ++tt)
            v += prb[(q + 4 * tt) * 4];
        v += __shfl_xor(v, 16, 64);
        v += __shfl_xor(v, 32, 64);

        if (lane < 16)
            out[(size_t)b * (P_TOT * 8) + (size_t)p * 8 + f] = v + bias[p * 8 + f];
    }
}

extern "C" void kernel_launch(void* const* d_in, const int* in_sizes, int n_in,
                              void* d_out, int out_size, void* d_ws, size_t ws_size,
                              hipStream_t stream) {
    const float* x    = (const float*)d_in[0];
    const float* kern = (const float*)d_in[1];
    const float* bias = (const float*)d_in[2];
    float* out        = (float*)d_out;

    lc3d_kernel<<<NBLK, 256, 0, stream>>>(x, kern, bias, out);
}